// Round 10
// baseline (229.731 us; speedup 1.0000x reference)
//
#include <hip/hip_runtime.h>
#include <hip/hip_fp16.h>
#include <math.h>

#define IN_CH 8
#define HID   64
#define EMB   32
#define SCAN_T 4096     // 16 blocks x 256 for the histogram scan
#define HBLK  256       // blocks in hist/scatter phases
#define BW    256       // nodes per bucket (dst >> 8)
#define BSH   8         // log2(BW)
#define NBMAX 400       // max buckets supported (N <= 102400)
#define P8SCALE 128.0f

static __device__ __forceinline__ __half2 u2h2(unsigned u) {
    union { unsigned u; __half2 h; } c; c.u = u; return c.h;
}
static __device__ __forceinline__ unsigned h22u(__half2 h) {
    union { unsigned u; __half2 h; } c; c.h = h; return c.u;
}
static __device__ __forceinline__ void acc4(int* acc, unsigned u) {
    acc[0] += (int)(signed char)(u);
    acc[1] += (int)(signed char)(u >> 8);
    acc[2] += (int)(signed char)(u >> 16);
    acc[3] += (int)(signed char)(u >> 24);
}

// ------------------------------------------------- x -> fp16 rows (16B)
__global__ __launch_bounds__(256) void xh_kernel(const float* __restrict__ x,
                                                 unsigned* __restrict__ xh, int N) {
    int n = blockIdx.x * 256 + threadIdx.x;
    if (n >= N) return;
    float4 a = ((const float4*)(x + (size_t)n * IN_CH))[0];
    float4 b = ((const float4*)(x + (size_t)n * IN_CH))[1];
    uint4 o;
    o.x = h22u(__floats2half2_rn(a.x, a.y));
    o.y = h22u(__floats2half2_rn(a.z, a.w));
    o.z = h22u(__floats2half2_rn(b.x, b.y));
    o.w = h22u(__floats2half2_rn(b.z, b.w));
    ((uint4*)(xh + (size_t)n * 4))[0] = o;
}

// ------------------------------------------------- pass A1: per-block bucket histogram
__global__ __launch_bounds__(256) void hist_kernel(const int* __restrict__ ei,
                                                   int* __restrict__ hist2, int E, int NB) {
    __shared__ int lh[NBMAX];
    int b = blockIdx.x, t = threadIdx.x;
    for (int i = t; i < NB; i += 256) lh[i] = 0;
    __syncthreads();
    int per = (E + gridDim.x - 1) / gridDim.x;
    int e0 = b * per, e1 = min(e0 + per, E);
    for (int e = e0 + t; e < e1; e += 256)
        atomicAdd(&lh[ei[E + e] >> BSH], 1);
    __syncthreads();
    for (int i = t; i < NB; i += 256) hist2[b * NB + i] = lh[i];
}

// ------------------------------------------------- hist scan (bucket-major logical order)
__global__ void hscanA_kernel(const int* __restrict__ hist2, int* __restrict__ tsum,
                              int M, int NB) {
    int tid = blockIdx.x * blockDim.x + threadIdx.x;
    int chunk = (M + SCAN_T - 1) / SCAN_T;
    int start = tid * chunk, end = min(start + chunk, M);
    int s = 0;
    for (int l = start; l < end; l++) s += hist2[(l & (HBLK - 1)) * NB + (l >> 8)];
    tsum[tid] = s;
}

__global__ __launch_bounds__(256) void hscanB_kernel(const int* __restrict__ tsum,
                                                     int* __restrict__ tpre) {
    __shared__ int bsum[256];
    int t = threadIdx.x;
    int s = 0;
    #pragma unroll
    for (int i = 0; i < 16; i++) s += tsum[t * 16 + i];
    bsum[t] = s;
    __syncthreads();
    for (int off = 1; off < 256; off <<= 1) {
        int v = (t >= off) ? bsum[t - off] : 0;
        __syncthreads();
        bsum[t] += v;
        __syncthreads();
    }
    int run = (t == 0) ? 0 : bsum[t - 1];
    #pragma unroll
    for (int i = 0; i < 16; i++) { tpre[t * 16 + i] = run; run += tsum[t * 16 + i]; }
}

__global__ void hscanC_kernel(const int* __restrict__ hist2, const int* __restrict__ tpre,
                              int* __restrict__ off2, int M, int NB) {
    int tid = blockIdx.x * blockDim.x + threadIdx.x;
    int chunk = (M + SCAN_T - 1) / SCAN_T;
    int start = tid * chunk, end = min(start + chunk, M);
    int run = tpre[tid];
    for (int l = start; l < end; l++) {
        int ph = (l & (HBLK - 1)) * NB + (l >> 8);
        off2[ph] = run;
        run += hist2[ph];
    }
}

// ------------------------------------------------- pass A2: scatter edges (packed src|li)
__global__ __launch_bounds__(256) void scat_kernel(const int* __restrict__ ei,
                                                   const int* __restrict__ off2,
                                                   int* __restrict__ staged, int E, int NB) {
    __shared__ int lcur[NBMAX];
    int b = blockIdx.x, t = threadIdx.x;
    for (int i = t; i < NB; i += 256) lcur[i] = off2[b * NB + i];
    __syncthreads();
    int per = (E + gridDim.x - 1) / gridDim.x;
    int e0 = b * per, e1 = min(e0 + per, E);
    for (int e = e0 + t; e < e1; e += 256) {
        int src = ei[e], dst = ei[E + e];
        int pos = atomicAdd(&lcur[dst >> BSH], 1);
        staged[pos] = src | ((dst & (BW - 1)) << 17);   // src<2^17, li<256
    }
}

// ------------------------------------------------- pass B: per-bucket CSR build
__global__ __launch_bounds__(256) void bucket_kernel(const int* __restrict__ staged,
                                                     const int* __restrict__ off2,
                                                     int* __restrict__ row_off,
                                                     int* __restrict__ csr,
                                                     int N, int E, int NB) {
    __shared__ int cnt[BW], offx[BW], cur[BW];
    int b = blockIdx.x, t = threadIdx.x;
    int base = b * BW;
    int s0 = off2[b];
    int s1 = (b + 1 < NB) ? off2[b + 1] : E;
    cnt[t] = 0;
    __syncthreads();
    for (int e = s0 + t; e < s1; e += 256)
        atomicAdd(&cnt[staged[e] >> 17], 1);
    __syncthreads();
    offx[t] = cnt[t];
    __syncthreads();
    for (int off = 1; off < BW; off <<= 1) {
        int v = (t >= off) ? offx[t - off] : 0;
        __syncthreads();
        offx[t] += v;
        __syncthreads();
    }
    {
        int ex = offx[t] - cnt[t];
        if (base + t < N) row_off[base + t] = s0 + ex;
        cnt[t] = ex;
        cur[t] = 0;
    }
    if (b == NB - 1 && t == 0) row_off[N] = s1;
    __syncthreads();
    for (int e = s0 + t; e < s1; e += 256) {
        int v = staged[e];
        int li = v >> 17;
        int pos = s0 + cnt[li] + atomicAdd(&cur[li], 1);
        csr[pos] = v & 0x1FFFF;
    }
}

// ------------------------------------------------- gather1: mean of fp16 x, 2 lanes/node
__global__ __launch_bounds__(256) void gather1_kernel(
        const unsigned* __restrict__ xh, const int* __restrict__ row_off,
        const int* __restrict__ csr, float* __restrict__ aggr, int N) {
    int t = threadIdx.x;
    int l = t >> 1, q = t & 1;
    int node = blockIdx.x * 128 + l;
    if (node >= N) return;
    int r0 = row_off[node], r1 = row_off[node + 1];
    int deg = r1 - r0;

    float a0 = 0.f, a1 = 0.f, a2 = 0.f, a3 = 0.f;
    int e = r0;
    for (; e + 4 <= r1; e += 4) {
        int i0 = csr[e], i1 = csr[e + 1], i2 = csr[e + 2], i3 = csr[e + 3];
        uint2 u0 = *(const uint2*)(xh + (size_t)i0 * 4 + q * 2);
        uint2 u1 = *(const uint2*)(xh + (size_t)i1 * 4 + q * 2);
        uint2 u2 = *(const uint2*)(xh + (size_t)i2 * 4 + q * 2);
        uint2 u3 = *(const uint2*)(xh + (size_t)i3 * 4 + q * 2);
        float2 f;
        f = __half22float2(u2h2(u0.x)); a0 += f.x; a1 += f.y;
        f = __half22float2(u2h2(u0.y)); a2 += f.x; a3 += f.y;
        f = __half22float2(u2h2(u1.x)); a0 += f.x; a1 += f.y;
        f = __half22float2(u2h2(u1.y)); a2 += f.x; a3 += f.y;
        f = __half22float2(u2h2(u2.x)); a0 += f.x; a1 += f.y;
        f = __half22float2(u2h2(u2.y)); a2 += f.x; a3 += f.y;
        f = __half22float2(u2h2(u3.x)); a0 += f.x; a1 += f.y;
        f = __half22float2(u2h2(u3.y)); a2 += f.x; a3 += f.y;
    }
    for (; e < r1; e++) {
        uint2 u0 = *(const uint2*)(xh + (size_t)csr[e] * 4 + q * 2);
        float2 f;
        f = __half22float2(u2h2(u0.x)); a0 += f.x; a1 += f.y;
        f = __half22float2(u2h2(u0.y)); a2 += f.x; a3 += f.y;
    }
    float inv = 1.0f / fmaxf((float)deg, 1.0f);
    ((float4*)(aggr + (size_t)node * IN_CH))[q] =
        make_float4(a0 * inv, a1 * inv, a2 * inv, a3 * inv);
}

// ------------------------------------------------- dense1b: 2 threads/node dense chain
// thread half owns j in [half*16, half*16+16): h recomputed per half;
// p8 = round(h@W2l * 128) int8; selfh = h@W2r + b2 (fp16).
__global__ __launch_bounds__(256) void dense1b_kernel(
        const float* __restrict__ x, const float* __restrict__ aggr,
        const float* __restrict__ W1l, const float* __restrict__ b1,
        const float* __restrict__ W1r,
        const float* __restrict__ W2l, const float* __restrict__ b2,
        const float* __restrict__ W2r,
        unsigned* __restrict__ p8, unsigned* __restrict__ selfh, int N) {
    int tid = blockIdx.x * 256 + threadIdx.x;
    int n = tid >> 1;
    int half = tid & 1;
    if (n >= N) return;

    float av[IN_CH], xv[IN_CH];
    {
        float4 a0 = ((const float4*)(aggr + (size_t)n * IN_CH))[0];
        float4 a1 = ((const float4*)(aggr + (size_t)n * IN_CH))[1];
        av[0] = a0.x; av[1] = a0.y; av[2] = a0.z; av[3] = a0.w;
        av[4] = a1.x; av[5] = a1.y; av[6] = a1.z; av[7] = a1.w;
        float4 b0 = ((const float4*)(x + (size_t)n * IN_CH))[0];
        float4 b1v = ((const float4*)(x + (size_t)n * IN_CH))[1];
        xv[0] = b0.x; xv[1] = b0.y; xv[2] = b0.z; xv[3] = b0.w;
        xv[4] = b1v.x; xv[5] = b1v.y; xv[6] = b1v.z; xv[7] = b1v.w;
    }

    float pacc[16], sacc[16];
    const float* W2lh = W2l + half * 16;
    const float* W2rh = W2r + half * 16;
    #pragma unroll
    for (int j = 0; j < 16; j++) { pacc[j] = 0.0f; sacc[j] = b2[half * 16 + j]; }

    #pragma unroll 4
    for (int k = 0; k < HID; k++) {
        float hk = b1[k];
        #pragma unroll
        for (int c = 0; c < IN_CH; c++)
            hk += av[c] * W1l[c * HID + k] + xv[c] * W1r[c * HID + k];
        hk = fmaxf(hk, 0.0f);
        #pragma unroll
        for (int j = 0; j < 16; j++) {
            pacc[j] += hk * W2lh[k * EMB + j];
            sacc[j] += hk * W2rh[k * EMB + j];
        }
    }

    unsigned up[4];
    #pragma unroll
    for (int m = 0; m < 4; m++) {
        int q0 = min(127, max(-127, __float2int_rn(pacc[4 * m + 0] * P8SCALE)));
        int q1 = min(127, max(-127, __float2int_rn(pacc[4 * m + 1] * P8SCALE)));
        int q2 = min(127, max(-127, __float2int_rn(pacc[4 * m + 2] * P8SCALE)));
        int q3 = min(127, max(-127, __float2int_rn(pacc[4 * m + 3] * P8SCALE)));
        up[m] = (unsigned)(q0 & 255) | ((unsigned)(q1 & 255) << 8)
              | ((unsigned)(q2 & 255) << 16) | ((unsigned)(q3 & 255) << 24);
    }
    ((uint4*)(p8 + (size_t)n * 8 + half * 4))[0] = make_uint4(up[0], up[1], up[2], up[3]);

    unsigned us[8];
    #pragma unroll
    for (int m = 0; m < 8; m++)
        us[m] = h22u(__floats2half2_rn(sacc[2 * m], sacc[2 * m + 1]));
    uint4* sp = (uint4*)(selfh + (size_t)n * 16 + half * 8);
    sp[0] = make_uint4(us[0], us[1], us[2], us[3]);
    sp[1] = make_uint4(us[4], us[5], us[6], us[7]);
}

// ------------------------------------------------- gather2: 4 lanes/node int8 + head
// lane q owns channels 8q..8q+7 (uint2 of the 32B int8 p-row). Exact int32
// accumulate, 64 nodes/block (1563 blocks). Phase 2: thread-per-node head MLP.
__global__ __launch_bounds__(256) void gather2_kernel(
        const unsigned* __restrict__ p8, const unsigned* __restrict__ selfh,
        const int* __restrict__ row_off, const int* __restrict__ csr,
        const float* __restrict__ Wh1, const float* __restrict__ bh1,
        const float* __restrict__ Wh2, const float* __restrict__ bh2,
        float* __restrict__ out, int N) {
    __shared__ float zs[64 * 34];     // pitch 34: 2-way max conflicts (free)
    __shared__ float sW1[EMB * 16];
    __shared__ float sbh1[16];
    __shared__ float sW2[16];
    __shared__ float sbh2;
    int t = threadIdx.x;
    for (int i = t; i < EMB * 16; i += 256) sW1[i] = Wh1[i];
    if (t < 16) { sbh1[t] = bh1[t]; sW2[t] = Wh2[t]; }
    if (t == 0) sbh2 = bh2[0];

    int l = t >> 2, q = t & 3;
    int node = blockIdx.x * 64 + l;

    if (node < N) {
        int r0 = row_off[node], r1 = row_off[node + 1];
        int deg = r1 - r0;

        int acc[8];
        #pragma unroll
        for (int j = 0; j < 8; j++) acc[j] = 0;

        int e = r0;
        for (; e + 4 <= r1; e += 4) {
            int i0 = csr[e], i1 = csr[e + 1], i2 = csr[e + 2], i3 = csr[e + 3];
            uint2 u0 = *(const uint2*)(p8 + (size_t)i0 * 8 + q * 2);
            uint2 u1 = *(const uint2*)(p8 + (size_t)i1 * 8 + q * 2);
            uint2 u2 = *(const uint2*)(p8 + (size_t)i2 * 8 + q * 2);
            uint2 u3 = *(const uint2*)(p8 + (size_t)i3 * 8 + q * 2);
            acc4(acc + 0, u0.x); acc4(acc + 4, u0.y);
            acc4(acc + 0, u1.x); acc4(acc + 4, u1.y);
            acc4(acc + 0, u2.x); acc4(acc + 4, u2.y);
            acc4(acc + 0, u3.x); acc4(acc + 4, u3.y);
        }
        for (; e < r1; e++) {
            uint2 u0 = *(const uint2*)(p8 + (size_t)csr[e] * 8 + q * 2);
            acc4(acc + 0, u0.x); acc4(acc + 4, u0.y);
        }

        float s = (1.0f / P8SCALE) / fmaxf((float)deg, 1.0f);
        uint4 sh = ((const uint4*)(selfh + (size_t)node * 16 + q * 4))[0];
        float sf[8];
        { float2 c = __half22float2(u2h2(sh.x)); sf[0] = c.x; sf[1] = c.y; }
        { float2 c = __half22float2(u2h2(sh.y)); sf[2] = c.x; sf[3] = c.y; }
        { float2 c = __half22float2(u2h2(sh.z)); sf[4] = c.x; sf[5] = c.y; }
        { float2 c = __half22float2(u2h2(sh.w)); sf[6] = c.x; sf[7] = c.y; }
        float* zrow = zs + l * 34 + q * 8;
        #pragma unroll
        for (int j = 0; j < 8; j++)
            zrow[j] = fmaxf((float)acc[j] * s + sf[j], 0.0f);
    }
    __syncthreads();

    if (t < 64) {
        int node2 = blockIdx.x * 64 + t;
        if (node2 < N) {
            float zr[EMB];
            #pragma unroll
            for (int k = 0; k < EMB; k++) zr[k] = zs[t * 34 + k];
            float logit = sbh2;
            #pragma unroll
            for (int i = 0; i < 16; i++) {
                float acc = sbh1[i];
                #pragma unroll
                for (int k = 0; k < EMB; k++) acc += zr[k] * sW1[k * 16 + i];
                logit += fmaxf(acc, 0.0f) * sW2[i];
            }
            out[node2] = 1.0f / (1.0f + expf(-logit));
        }
    }
}

// ---------------------------------------------------------------- launch
extern "C" void kernel_launch(void* const* d_in, const int* in_sizes, int n_in,
                              void* d_out, int out_size, void* d_ws, size_t ws_size,
                              hipStream_t stream) {
    const float* x   = (const float*)d_in[0];
    const int*   ei  = (const int*)d_in[1];
    const float* W1l = (const float*)d_in[2];
    const float* b1  = (const float*)d_in[3];
    const float* W1r = (const float*)d_in[4];
    const float* W2l = (const float*)d_in[5];
    const float* b2  = (const float*)d_in[6];
    const float* W2r = (const float*)d_in[7];
    const float* Wh1 = (const float*)d_in[8];
    const float* bh1 = (const float*)d_in[9];
    const float* Wh2 = (const float*)d_in[10];
    const float* bh2 = (const float*)d_in[11];

    int N = in_sizes[0] / IN_CH;     // 100000
    int E = in_sizes[1] / 2;         // 3200000
    int NB = (N + BW - 1) / BW;      // 391 buckets
    int M  = NB * HBLK;              // histogram cells

    // workspace layout:
    // [staged int E][hist2 M][off2 M][tsum 4096][tpre 4096][row_off N+1][csr E]
    // [xh 4N u32][aggr 8N f32][selfh 16N u32][p8 8N u32]
    int* staged   = (int*)d_ws;
    int* hist2    = staged + E;
    int* off2     = hist2 + M;
    int* tsum     = off2 + M;
    int* tpre     = tsum + SCAN_T;
    int* row_off  = tpre + SCAN_T;
    int* csr      = row_off + (N + 1);
    unsigned* xh  = (unsigned*)(csr + E);
    float* aggr   = (float*)(xh + (size_t)N * 4);
    unsigned* selfh = (unsigned*)(aggr + (size_t)N * IN_CH);
    unsigned* p8  = selfh + (size_t)N * 16;

    xh_kernel     <<<(N + 255) / 256, 256, 0, stream>>>(x, xh, N);
    hist_kernel   <<<HBLK, 256, 0, stream>>>(ei, hist2, E, NB);
    hscanA_kernel <<<SCAN_T / 256, 256, 0, stream>>>(hist2, tsum, M, NB);
    hscanB_kernel <<<1, 256, 0, stream>>>(tsum, tpre);
    hscanC_kernel <<<SCAN_T / 256, 256, 0, stream>>>(hist2, tpre, off2, M, NB);
    scat_kernel   <<<HBLK, 256, 0, stream>>>(ei, off2, staged, E, NB);
    bucket_kernel <<<NB, 256, 0, stream>>>(staged, off2, row_off, csr, N, E, NB);
    gather1_kernel<<<(N + 127) / 128, 256, 0, stream>>>(xh, row_off, csr, aggr, N);
    dense1b_kernel<<<(N * 2 + 255) / 256, 256, 0, stream>>>(x, aggr, W1l, b1, W1r,
                                                            W2l, b2, W2r, p8, selfh, N);
    gather2_kernel<<<(N + 63) / 64, 256, 0, stream>>>(p8, selfh, row_off, csr,
                                                      Wh1, bh1, Wh2, bh2, (float*)d_out, N);
}

// Round 11
// 212.053 us; speedup vs baseline: 1.0834x; 1.0834x over previous
//
#include <hip/hip_runtime.h>
#include <hip/hip_fp16.h>
#include <math.h>

#define IN_CH 8
#define HID   64
#define EMB   32
#define SCAN_T 4096     // 16 blocks x 256 for the histogram scan
#define HBLK  256       // blocks in hist/scatter phases
#define BW    256       // nodes per bucket (dst >> 8)
#define BSH   8         // log2(BW)
#define NBMAX 400       // max buckets supported (N <= 102400)
#define P8SCALE 128.0f

typedef _Float16 half2n __attribute__((ext_vector_type(2)));

static __device__ __forceinline__ __half2 u2h2(unsigned u) {
    union { unsigned u; __half2 h; } c; c.u = u; return c.h;
}
static __device__ __forceinline__ unsigned h22u(__half2 h) {
    union { unsigned u; __half2 h; } c; c.h = h; return c.u;
}
static __device__ __forceinline__ half2n u2n(unsigned u) {
    union { unsigned u; half2n h; } c; c.u = u; return c.h;
}
static __device__ __forceinline__ half2n mkh2(float a, float b) {
    half2n r; r.x = (_Float16)a; r.y = (_Float16)b; return r;
}
static __device__ __forceinline__ float fdot2w(half2n a, half2n b, float c) {
#if __has_builtin(__builtin_amdgcn_fdot2)
    return __builtin_amdgcn_fdot2(a, b, c, false);
#else
    return (float)a.x * (float)b.x + (float)a.y * (float)b.y + c;
#endif
}
static __device__ __forceinline__ void acc4(int* acc, unsigned u) {
    acc[0] += (int)(signed char)(u);
    acc[1] += (int)(signed char)(u >> 8);
    acc[2] += (int)(signed char)(u >> 16);
    acc[3] += (int)(signed char)(u >> 24);
}

// ------------------------------------------------- x -> fp16 rows (16B)
__global__ __launch_bounds__(256) void xh_kernel(const float* __restrict__ x,
                                                 unsigned* __restrict__ xh, int N) {
    int n = blockIdx.x * 256 + threadIdx.x;
    if (n >= N) return;
    float4 a = ((const float4*)(x + (size_t)n * IN_CH))[0];
    float4 b = ((const float4*)(x + (size_t)n * IN_CH))[1];
    uint4 o;
    o.x = h22u(__floats2half2_rn(a.x, a.y));
    o.y = h22u(__floats2half2_rn(a.z, a.w));
    o.z = h22u(__floats2half2_rn(b.x, b.y));
    o.w = h22u(__floats2half2_rn(b.z, b.w));
    ((uint4*)(xh + (size_t)n * 4))[0] = o;
}

// ------------------------------------------------- pack weights to fp16 pairs (10KB, fits sL1)
// w1p[k*8+c]  = (W1l[c][k], W1r[c][k])            : dot with (aggr_c, x_c)
// w2lp[k2*32+j] = (W2l[2k2][j], W2l[2k2+1][j])    : dot with (h_2k2, h_2k2+1)
// w2rp likewise for W2r.
__global__ __launch_bounds__(256) void wpack_kernel(
        const float* __restrict__ W1l, const float* __restrict__ W1r,
        const float* __restrict__ W2l, const float* __restrict__ W2r,
        unsigned* __restrict__ w1p, unsigned* __restrict__ w2lp,
        unsigned* __restrict__ w2rp) {
    int t = threadIdx.x;
    for (int i = t; i < HID * IN_CH; i += 256) {
        int k = i >> 3, c = i & 7;
        w1p[i] = h22u(__floats2half2_rn(W1l[c * HID + k], W1r[c * HID + k]));
    }
    for (int i = t; i < (HID / 2) * EMB; i += 256) {
        int k2 = i >> 5, j = i & 31;
        w2lp[i] = h22u(__floats2half2_rn(W2l[(2 * k2) * EMB + j], W2l[(2 * k2 + 1) * EMB + j]));
        w2rp[i] = h22u(__floats2half2_rn(W2r[(2 * k2) * EMB + j], W2r[(2 * k2 + 1) * EMB + j]));
    }
}

// ------------------------------------------------- pass A1: per-block bucket histogram
__global__ __launch_bounds__(256) void hist_kernel(const int* __restrict__ ei,
                                                   int* __restrict__ hist2, int E, int NB) {
    __shared__ int lh[NBMAX];
    int b = blockIdx.x, t = threadIdx.x;
    for (int i = t; i < NB; i += 256) lh[i] = 0;
    __syncthreads();
    int per = (E + gridDim.x - 1) / gridDim.x;
    int e0 = b * per, e1 = min(e0 + per, E);
    for (int e = e0 + t; e < e1; e += 256)
        atomicAdd(&lh[ei[E + e] >> BSH], 1);
    __syncthreads();
    for (int i = t; i < NB; i += 256) hist2[b * NB + i] = lh[i];
}

// ------------------------------------------------- hist scan (bucket-major logical order)
__global__ void hscanA_kernel(const int* __restrict__ hist2, int* __restrict__ tsum,
                              int M, int NB) {
    int tid = blockIdx.x * blockDim.x + threadIdx.x;
    int chunk = (M + SCAN_T - 1) / SCAN_T;
    int start = tid * chunk, end = min(start + chunk, M);
    int s = 0;
    for (int l = start; l < end; l++) s += hist2[(l & (HBLK - 1)) * NB + (l >> 8)];
    tsum[tid] = s;
}

__global__ __launch_bounds__(256) void hscanB_kernel(const int* __restrict__ tsum,
                                                     int* __restrict__ tpre) {
    __shared__ int bsum[256];
    int t = threadIdx.x;
    int s = 0;
    #pragma unroll
    for (int i = 0; i < 16; i++) s += tsum[t * 16 + i];
    bsum[t] = s;
    __syncthreads();
    for (int off = 1; off < 256; off <<= 1) {
        int v = (t >= off) ? bsum[t - off] : 0;
        __syncthreads();
        bsum[t] += v;
        __syncthreads();
    }
    int run = (t == 0) ? 0 : bsum[t - 1];
    #pragma unroll
    for (int i = 0; i < 16; i++) { tpre[t * 16 + i] = run; run += tsum[t * 16 + i]; }
}

__global__ void hscanC_kernel(const int* __restrict__ hist2, const int* __restrict__ tpre,
                              int* __restrict__ off2, int M, int NB) {
    int tid = blockIdx.x * blockDim.x + threadIdx.x;
    int chunk = (M + SCAN_T - 1) / SCAN_T;
    int start = tid * chunk, end = min(start + chunk, M);
    int run = tpre[tid];
    for (int l = start; l < end; l++) {
        int ph = (l & (HBLK - 1)) * NB + (l >> 8);
        off2[ph] = run;
        run += hist2[ph];
    }
}

// ------------------------------------------------- pass A2: scatter edges (packed src|li)
__global__ __launch_bounds__(256) void scat_kernel(const int* __restrict__ ei,
                                                   const int* __restrict__ off2,
                                                   int* __restrict__ staged, int E, int NB) {
    __shared__ int lcur[NBMAX];
    int b = blockIdx.x, t = threadIdx.x;
    for (int i = t; i < NB; i += 256) lcur[i] = off2[b * NB + i];
    __syncthreads();
    int per = (E + gridDim.x - 1) / gridDim.x;
    int e0 = b * per, e1 = min(e0 + per, E);
    for (int e = e0 + t; e < e1; e += 256) {
        int src = ei[e], dst = ei[E + e];
        int pos = atomicAdd(&lcur[dst >> BSH], 1);
        staged[pos] = src | ((dst & (BW - 1)) << 17);   // src<2^17, li<256
    }
}

// ------------------------------------------------- pass B: per-bucket CSR build
__global__ __launch_bounds__(256) void bucket_kernel(const int* __restrict__ staged,
                                                     const int* __restrict__ off2,
                                                     int* __restrict__ row_off,
                                                     int* __restrict__ csr,
                                                     int N, int E, int NB) {
    __shared__ int cnt[BW], offx[BW], cur[BW];
    int b = blockIdx.x, t = threadIdx.x;
    int base = b * BW;
    int s0 = off2[b];
    int s1 = (b + 1 < NB) ? off2[b + 1] : E;
    cnt[t] = 0;
    __syncthreads();
    for (int e = s0 + t; e < s1; e += 256)
        atomicAdd(&cnt[staged[e] >> 17], 1);
    __syncthreads();
    offx[t] = cnt[t];
    __syncthreads();
    for (int off = 1; off < BW; off <<= 1) {
        int v = (t >= off) ? offx[t - off] : 0;
        __syncthreads();
        offx[t] += v;
        __syncthreads();
    }
    {
        int ex = offx[t] - cnt[t];
        if (base + t < N) row_off[base + t] = s0 + ex;
        cnt[t] = ex;
        cur[t] = 0;
    }
    if (b == NB - 1 && t == 0) row_off[N] = s1;
    __syncthreads();
    for (int e = s0 + t; e < s1; e += 256) {
        int v = staged[e];
        int li = v >> 17;
        int pos = s0 + cnt[li] + atomicAdd(&cur[li], 1);
        csr[pos] = v & 0x1FFFF;
    }
}

// ------------------------------------------------- gather1: mean of fp16 x, 2 lanes/node
__global__ __launch_bounds__(256) void gather1_kernel(
        const unsigned* __restrict__ xh, const int* __restrict__ row_off,
        const int* __restrict__ csr, float* __restrict__ aggr, int N) {
    int t = threadIdx.x;
    int l = t >> 1, q = t & 1;
    int node = blockIdx.x * 128 + l;
    if (node >= N) return;
    int r0 = row_off[node], r1 = row_off[node + 1];
    int deg = r1 - r0;

    float a0 = 0.f, a1 = 0.f, a2 = 0.f, a3 = 0.f;
    int e = r0;
    for (; e + 4 <= r1; e += 4) {
        int i0 = csr[e], i1 = csr[e + 1], i2 = csr[e + 2], i3 = csr[e + 3];
        uint2 u0 = *(const uint2*)(xh + (size_t)i0 * 4 + q * 2);
        uint2 u1 = *(const uint2*)(xh + (size_t)i1 * 4 + q * 2);
        uint2 u2 = *(const uint2*)(xh + (size_t)i2 * 4 + q * 2);
        uint2 u3 = *(const uint2*)(xh + (size_t)i3 * 4 + q * 2);
        float2 f;
        f = __half22float2(u2h2(u0.x)); a0 += f.x; a1 += f.y;
        f = __half22float2(u2h2(u0.y)); a2 += f.x; a3 += f.y;
        f = __half22float2(u2h2(u1.x)); a0 += f.x; a1 += f.y;
        f = __half22float2(u2h2(u1.y)); a2 += f.x; a3 += f.y;
        f = __half22float2(u2h2(u2.x)); a0 += f.x; a1 += f.y;
        f = __half22float2(u2h2(u2.y)); a2 += f.x; a3 += f.y;
        f = __half22float2(u2h2(u3.x)); a0 += f.x; a1 += f.y;
        f = __half22float2(u2h2(u3.y)); a2 += f.x; a3 += f.y;
    }
    for (; e < r1; e++) {
        uint2 u0 = *(const uint2*)(xh + (size_t)csr[e] * 4 + q * 2);
        float2 f;
        f = __half22float2(u2h2(u0.x)); a0 += f.x; a1 += f.y;
        f = __half22float2(u2h2(u0.y)); a2 += f.x; a3 += f.y;
    }
    float inv = 1.0f / fmaxf((float)deg, 1.0f);
    ((float4*)(aggr + (size_t)node * IN_CH))[q] =
        make_float4(a0 * inv, a1 * inv, a2 * inv, a3 * inv);
}

// ------------------------------------------------- dense1b: node-per-thread, fp16 dot2
// All weight reads wave-uniform (s_load, 10KB stream fits scalar L1).
// h-pair per k2 via fdot2 on (aggr,x) pairs; p/self via fdot2 on (h0,h1) pairs.
__global__ __launch_bounds__(256) void dense1b_kernel(
        const float* __restrict__ x, const float* __restrict__ aggr,
        const float* __restrict__ b1, const float* __restrict__ b2,
        const unsigned* __restrict__ w1p, const unsigned* __restrict__ w2lp,
        const unsigned* __restrict__ w2rp,
        unsigned* __restrict__ p8, unsigned* __restrict__ selfh, int N) {
    int n = blockIdx.x * 256 + threadIdx.x;
    if (n >= N) return;

    half2n uv[IN_CH];
    {
        float4 a0 = ((const float4*)(aggr + (size_t)n * IN_CH))[0];
        float4 a1 = ((const float4*)(aggr + (size_t)n * IN_CH))[1];
        float4 b0 = ((const float4*)(x + (size_t)n * IN_CH))[0];
        float4 b1v = ((const float4*)(x + (size_t)n * IN_CH))[1];
        uv[0] = mkh2(a0.x, b0.x); uv[1] = mkh2(a0.y, b0.y);
        uv[2] = mkh2(a0.z, b0.z); uv[3] = mkh2(a0.w, b0.w);
        uv[4] = mkh2(a1.x, b1v.x); uv[5] = mkh2(a1.y, b1v.y);
        uv[6] = mkh2(a1.z, b1v.z); uv[7] = mkh2(a1.w, b1v.w);
    }

    float pacc[EMB], sacc[EMB];
    #pragma unroll
    for (int j = 0; j < EMB; j++) { pacc[j] = 0.0f; sacc[j] = b2[j]; }

    #pragma unroll 2
    for (int k2 = 0; k2 < HID / 2; k2++) {
        int k = 2 * k2;
        float h0 = b1[k], h1 = b1[k + 1];
        #pragma unroll
        for (int c = 0; c < IN_CH; c++) {
            h0 = fdot2w(uv[c], u2n(w1p[k * 8 + c]), h0);
            h1 = fdot2w(uv[c], u2n(w1p[(k + 1) * 8 + c]), h1);
        }
        h0 = fmaxf(h0, 0.0f);
        h1 = fmaxf(h1, 0.0f);
        half2n hh = mkh2(h0, h1);
        #pragma unroll
        for (int j = 0; j < EMB; j++) {
            pacc[j] = fdot2w(hh, u2n(w2lp[k2 * EMB + j]), pacc[j]);
            sacc[j] = fdot2w(hh, u2n(w2rp[k2 * EMB + j]), sacc[j]);
        }
    }

    unsigned up[8];
    #pragma unroll
    for (int m = 0; m < 8; m++) {
        int q0 = min(127, max(-127, __float2int_rn(pacc[4 * m + 0] * P8SCALE)));
        int q1 = min(127, max(-127, __float2int_rn(pacc[4 * m + 1] * P8SCALE)));
        int q2 = min(127, max(-127, __float2int_rn(pacc[4 * m + 2] * P8SCALE)));
        int q3 = min(127, max(-127, __float2int_rn(pacc[4 * m + 3] * P8SCALE)));
        up[m] = (unsigned)(q0 & 255) | ((unsigned)(q1 & 255) << 8)
              | ((unsigned)(q2 & 255) << 16) | ((unsigned)(q3 & 255) << 24);
    }
    uint4* pp = (uint4*)(p8 + (size_t)n * 8);
    pp[0] = make_uint4(up[0], up[1], up[2], up[3]);
    pp[1] = make_uint4(up[4], up[5], up[6], up[7]);

    unsigned us[16];
    #pragma unroll
    for (int m = 0; m < 16; m++)
        us[m] = h22u(__floats2half2_rn(sacc[2 * m], sacc[2 * m + 1]));
    uint4* sp = (uint4*)(selfh + (size_t)n * 16);
    sp[0] = make_uint4(us[0], us[1], us[2], us[3]);
    sp[1] = make_uint4(us[4], us[5], us[6], us[7]);
    sp[2] = make_uint4(us[8], us[9], us[10], us[11]);
    sp[3] = make_uint4(us[12], us[13], us[14], us[15]);
}

// ------------------------------------------------- gather2: 4 lanes/node int8 + head
__global__ __launch_bounds__(256) void gather2_kernel(
        const unsigned* __restrict__ p8, const unsigned* __restrict__ selfh,
        const int* __restrict__ row_off, const int* __restrict__ csr,
        const float* __restrict__ Wh1, const float* __restrict__ bh1,
        const float* __restrict__ Wh2, const float* __restrict__ bh2,
        float* __restrict__ out, int N) {
    __shared__ float zs[64 * 34];     // pitch 34: 2-way max conflicts (free)
    __shared__ float sW1[EMB * 16];
    __shared__ float sbh1[16];
    __shared__ float sW2[16];
    __shared__ float sbh2;
    int t = threadIdx.x;
    for (int i = t; i < EMB * 16; i += 256) sW1[i] = Wh1[i];
    if (t < 16) { sbh1[t] = bh1[t]; sW2[t] = Wh2[t]; }
    if (t == 0) sbh2 = bh2[0];

    int l = t >> 2, q = t & 3;
    int node = blockIdx.x * 64 + l;

    if (node < N) {
        int r0 = row_off[node], r1 = row_off[node + 1];
        int deg = r1 - r0;

        int acc[8];
        #pragma unroll
        for (int j = 0; j < 8; j++) acc[j] = 0;

        int e = r0;
        for (; e + 4 <= r1; e += 4) {
            int i0 = csr[e], i1 = csr[e + 1], i2 = csr[e + 2], i3 = csr[e + 3];
            uint2 u0 = *(const uint2*)(p8 + (size_t)i0 * 8 + q * 2);
            uint2 u1 = *(const uint2*)(p8 + (size_t)i1 * 8 + q * 2);
            uint2 u2 = *(const uint2*)(p8 + (size_t)i2 * 8 + q * 2);
            uint2 u3 = *(const uint2*)(p8 + (size_t)i3 * 8 + q * 2);
            acc4(acc + 0, u0.x); acc4(acc + 4, u0.y);
            acc4(acc + 0, u1.x); acc4(acc + 4, u1.y);
            acc4(acc + 0, u2.x); acc4(acc + 4, u2.y);
            acc4(acc + 0, u3.x); acc4(acc + 4, u3.y);
        }
        for (; e < r1; e++) {
            uint2 u0 = *(const uint2*)(p8 + (size_t)csr[e] * 8 + q * 2);
            acc4(acc + 0, u0.x); acc4(acc + 4, u0.y);
        }

        float s = (1.0f / P8SCALE) / fmaxf((float)deg, 1.0f);
        uint4 sh = ((const uint4*)(selfh + (size_t)node * 16 + q * 4))[0];
        float sf[8];
        { float2 c = __half22float2(u2h2(sh.x)); sf[0] = c.x; sf[1] = c.y; }
        { float2 c = __half22float2(u2h2(sh.y)); sf[2] = c.x; sf[3] = c.y; }
        { float2 c = __half22float2(u2h2(sh.z)); sf[4] = c.x; sf[5] = c.y; }
        { float2 c = __half22float2(u2h2(sh.w)); sf[6] = c.x; sf[7] = c.y; }
        float* zrow = zs + l * 34 + q * 8;
        #pragma unroll
        for (int j = 0; j < 8; j++)
            zrow[j] = fmaxf((float)acc[j] * s + sf[j], 0.0f);
    }
    __syncthreads();

    if (t < 64) {
        int node2 = blockIdx.x * 64 + t;
        if (node2 < N) {
            float zr[EMB];
            #pragma unroll
            for (int k = 0; k < EMB; k++) zr[k] = zs[t * 34 + k];
            float logit = sbh2;
            #pragma unroll
            for (int i = 0; i < 16; i++) {
                float acc = sbh1[i];
                #pragma unroll
                for (int k = 0; k < EMB; k++) acc += zr[k] * sW1[k * 16 + i];
                logit += fmaxf(acc, 0.0f) * sW2[i];
            }
            out[node2] = 1.0f / (1.0f + expf(-logit));
        }
    }
}

// ---------------------------------------------------------------- launch
extern "C" void kernel_launch(void* const* d_in, const int* in_sizes, int n_in,
                              void* d_out, int out_size, void* d_ws, size_t ws_size,
                              hipStream_t stream) {
    const float* x   = (const float*)d_in[0];
    const int*   ei  = (const int*)d_in[1];
    const float* W1l = (const float*)d_in[2];
    const float* b1  = (const float*)d_in[3];
    const float* W1r = (const float*)d_in[4];
    const float* W2l = (const float*)d_in[5];
    const float* b2  = (const float*)d_in[6];
    const float* W2r = (const float*)d_in[7];
    const float* Wh1 = (const float*)d_in[8];
    const float* bh1 = (const float*)d_in[9];
    const float* Wh2 = (const float*)d_in[10];
    const float* bh2 = (const float*)d_in[11];

    int N = in_sizes[0] / IN_CH;     // 100000
    int E = in_sizes[1] / 2;         // 3200000
    int NB = (N + BW - 1) / BW;      // 391 buckets
    int M  = NB * HBLK;              // histogram cells

    // workspace layout:
    // [staged int E][hist2 M][off2 M][tsum 4096][tpre 4096][row_off N+1][csr E]
    // [xh 4N u32][aggr 8N f32][selfh 16N u32][p8 8N u32][w1p 512][w2lp 1024][w2rp 1024]
    int* staged   = (int*)d_ws;
    int* hist2    = staged + E;
    int* off2     = hist2 + M;
    int* tsum     = off2 + M;
    int* tpre     = tsum + SCAN_T;
    int* row_off  = tpre + SCAN_T;
    int* csr      = row_off + (N + 1);
    unsigned* xh  = (unsigned*)(csr + E);
    float* aggr   = (float*)(xh + (size_t)N * 4);
    unsigned* selfh = (unsigned*)(aggr + (size_t)N * IN_CH);
    unsigned* p8  = selfh + (size_t)N * 16;
    unsigned* w1p = p8 + (size_t)N * 8;
    unsigned* w2lp = w1p + HID * IN_CH;
    unsigned* w2rp = w2lp + (HID / 2) * EMB;

    xh_kernel     <<<(N + 255) / 256, 256, 0, stream>>>(x, xh, N);
    wpack_kernel  <<<1, 256, 0, stream>>>(W1l, W1r, W2l, W2r, w1p, w2lp, w2rp);
    hist_kernel   <<<HBLK, 256, 0, stream>>>(ei, hist2, E, NB);
    hscanA_kernel <<<SCAN_T / 256, 256, 0, stream>>>(hist2, tsum, M, NB);
    hscanB_kernel <<<1, 256, 0, stream>>>(tsum, tpre);
    hscanC_kernel <<<SCAN_T / 256, 256, 0, stream>>>(hist2, tpre, off2, M, NB);
    scat_kernel   <<<HBLK, 256, 0, stream>>>(ei, off2, staged, E, NB);
    bucket_kernel <<<NB, 256, 0, stream>>>(staged, off2, row_off, csr, N, E, NB);
    gather1_kernel<<<(N + 127) / 128, 256, 0, stream>>>(xh, row_off, csr, aggr, N);
    dense1b_kernel<<<(N + 255) / 256, 256, 0, stream>>>(x, aggr, b1, b2,
                                                        w1p, w2lp, w2rp, p8, selfh, N);
    gather2_kernel<<<(N + 63) / 64, 256, 0, stream>>>(p8, selfh, row_off, csr,
                                                      Wh1, bh1, Wh2, bh2, (float*)d_out, N);
}